// Round 1
// baseline (1900.568 us; speedup 1.0000x reference)
//
#include <hip/hip_runtime.h>
#include <math.h>

#define BB 2
#define SS 2048
#define DM 1024
#define NH 16
#define HD 64

// ---------------- QKV projection: out[i,j] = sum_k X[i,k]*W[j,k] ----------------
// Writes to (b,h,s,hd) layout. 64x64 tile per block, 256 threads, 4x4 per thread.
// Column mapping is strided (c = tc + 16*j) so LDS reads of the W tile are <=2-way.
__global__ __launch_bounds__(256)
void qkv_gemm(const float* __restrict__ X,
              const float* __restrict__ Wq,
              const float* __restrict__ Wk,
              const float* __restrict__ Wv,
              float* __restrict__ Q, float* __restrict__ K, float* __restrict__ V)
{
    const float* W; float* dst;
    switch (blockIdx.z) {
        case 0:  W = Wq; dst = Q; break;
        case 1:  W = Wk; dst = K; break;
        default: W = Wv; dst = V; break;
    }
    __shared__ alignas(16) float xs[64][68];
    __shared__ alignas(16) float ws[64][68];
    const int t  = threadIdx.x;
    const int tr = t >> 4, tc = t & 15;
    const int i0 = blockIdx.y * 64, j0 = blockIdx.x * 64;
    const int rl = t >> 4, cl = (t & 15) * 4;
    float acc[4][4] = {};
    for (int k0 = 0; k0 < DM; k0 += 64) {
        #pragma unroll
        for (int rr = 0; rr < 4; ++rr) {
            int row = rl + rr * 16;
            *(float4*)&xs[row][cl] = *(const float4*)&X[(size_t)(i0 + row) * DM + k0 + cl];
            *(float4*)&ws[row][cl] = *(const float4*)&W[(size_t)(j0 + row) * DM + k0 + cl];
        }
        __syncthreads();
        #pragma unroll
        for (int kk = 0; kk < 64; kk += 4) {
            float4 a[4], b[4];
            #pragma unroll
            for (int i = 0; i < 4; ++i) a[i] = *(float4*)&xs[tr * 4 + i][kk];
            #pragma unroll
            for (int j = 0; j < 4; ++j) b[j] = *(float4*)&ws[tc + 16 * j][kk];
            #pragma unroll
            for (int i = 0; i < 4; ++i)
                #pragma unroll
                for (int j = 0; j < 4; ++j)
                    acc[i][j] += a[i].x * b[j].x + a[i].y * b[j].y
                               + a[i].z * b[j].z + a[i].w * b[j].w;
        }
        __syncthreads();
    }
    #pragma unroll
    for (int i = 0; i < 4; ++i) {
        int gi = i0 + tr * 4 + i;
        int b = gi >> 11, s = gi & 2047;
        #pragma unroll
        for (int j = 0; j < 4; ++j) {
            int gj = j0 + tc + 16 * j;
            int h = gj >> 6, hd = gj & 63;
            dst[(((size_t)(b * NH + h)) * SS + s) * HD + hd] = acc[i][j];
        }
    }
}

// ---------------- Output projection: out[i,j] = sum_k X[i,k]*W[j,k], flat (i,j) ----------------
__global__ __launch_bounds__(256)
void out_gemm(const float* __restrict__ X, const float* __restrict__ W,
              float* __restrict__ dst)
{
    __shared__ alignas(16) float xs[64][68];
    __shared__ alignas(16) float ws[64][68];
    const int t  = threadIdx.x;
    const int tr = t >> 4, tc = t & 15;
    const int i0 = blockIdx.y * 64, j0 = blockIdx.x * 64;
    const int rl = t >> 4, cl = (t & 15) * 4;
    float acc[4][4] = {};
    for (int k0 = 0; k0 < DM; k0 += 64) {
        #pragma unroll
        for (int rr = 0; rr < 4; ++rr) {
            int row = rl + rr * 16;
            *(float4*)&xs[row][cl] = *(const float4*)&X[(size_t)(i0 + row) * DM + k0 + cl];
            *(float4*)&ws[row][cl] = *(const float4*)&W[(size_t)(j0 + row) * DM + k0 + cl];
        }
        __syncthreads();
        #pragma unroll
        for (int kk = 0; kk < 64; kk += 4) {
            float4 a[4], b[4];
            #pragma unroll
            for (int i = 0; i < 4; ++i) a[i] = *(float4*)&xs[tr * 4 + i][kk];
            #pragma unroll
            for (int j = 0; j < 4; ++j) b[j] = *(float4*)&ws[tc + 16 * j][kk];
            #pragma unroll
            for (int i = 0; i < 4; ++i)
                #pragma unroll
                for (int j = 0; j < 4; ++j)
                    acc[i][j] += a[i].x * b[j].x + a[i].y * b[j].y
                               + a[i].z * b[j].z + a[i].w * b[j].w;
        }
        __syncthreads();
    }
    #pragma unroll
    for (int i = 0; i < 4; ++i) {
        int gi = i0 + tr * 4 + i;
        #pragma unroll
        for (int j = 0; j < 4; ++j) {
            int gj = j0 + tc + 16 * j;
            dst[(size_t)gi * DM + gj] = acc[i][j];
        }
    }
}

// ---------------- RoPE on Q and K, (b,h,s,hd) layout, interleaved pairs ----------------
__global__ __launch_bounds__(256)
void rope_kernel(float* __restrict__ Q, float* __restrict__ Kt,
                 const int* __restrict__ tp, const float* __restrict__ cosp,
                 const float* __restrict__ sinp, const int* __restrict__ use_rope)
{
    if (use_rope[0] == 0) return;
    int idx = blockIdx.x * 256 + threadIdx.x;   // over B*H*S*32 pairs
    int p  = idx & 31;
    int s  = (idx >> 5) & 2047;
    int bh = idx >> 16;                          // 32*2048 = 65536
    int pos = tp[s];
    float c  = cosp[pos * 32 + p];
    float sn = sinp[pos * 32 + p];
    size_t base = ((size_t)bh * SS + s) * HD + 2 * p;
    float2 q = *(float2*)&Q[base];
    float2 k = *(float2*)&Kt[base];
    *(float2*)&Q[base]  = make_float2(q.x * c - q.y * sn, q.y * c + q.x * sn);
    *(float2*)&Kt[base] = make_float2(k.x * c - k.y * sn, k.y * c + k.x * sn);
}

// ---------------- Flash attention: one block per (bh, 64-row q tile) ----------------
__global__ __launch_bounds__(256)
void attn_kernel(const float* __restrict__ Q, const float* __restrict__ K,
                 const float* __restrict__ V, float* __restrict__ Y)
{
    __shared__ alignas(16) float qs[64][68];
    __shared__ alignas(16) float ks[64][68];   // reused as P after scores computed
    __shared__ alignas(16) float vs[64][68];
    const int t  = threadIdx.x;
    const int tr = t >> 4, tc = t & 15;
    const int q0 = blockIdx.x * 64;
    const int bh = blockIdx.y;
    const float* Qp = Q + (size_t)bh * SS * HD;
    const float* Kp = K + (size_t)bh * SS * HD;
    const float* Vp = V + (size_t)bh * SS * HD;
    const int rl = t >> 4, cl = (t & 15) * 4;

    // load q tile, fold in 1/sqrt(HD)
    #pragma unroll
    for (int rr = 0; rr < 4; ++rr) {
        int row = rl + rr * 16;
        float4 v = *(const float4*)&Qp[(size_t)(q0 + row) * HD + cl];
        v.x *= 0.125f; v.y *= 0.125f; v.z *= 0.125f; v.w *= 0.125f;
        *(float4*)&qs[row][cl] = v;
    }

    float acc[4][4] = {};
    float m_i[4], l_i[4];
    #pragma unroll
    for (int i = 0; i < 4; ++i) { m_i[i] = -3.0e38f; l_i[i] = 0.f; }

    const int ntile = q0 / 64 + 1;
    for (int tix = 0; tix < ntile; ++tix) {
        const int j0 = tix * 64;
        __syncthreads();   // qs visible (iter 0); ks/vs free from previous PV
        #pragma unroll
        for (int rr = 0; rr < 4; ++rr) {
            int row = rl + rr * 16;
            *(float4*)&ks[row][cl] = *(const float4*)&Kp[(size_t)(j0 + row) * HD + cl];
            *(float4*)&vs[row][cl] = *(const float4*)&Vp[(size_t)(j0 + row) * HD + cl];
        }
        __syncthreads();

        // S = q . k
        float sc[4][4] = {};
        #pragma unroll
        for (int d = 0; d < 64; d += 4) {
            float4 a[4], b[4];
            #pragma unroll
            for (int i = 0; i < 4; ++i) a[i] = *(float4*)&qs[tr * 4 + i][d];
            #pragma unroll
            for (int j = 0; j < 4; ++j) b[j] = *(float4*)&ks[tc + 16 * j][d];
            #pragma unroll
            for (int i = 0; i < 4; ++i)
                #pragma unroll
                for (int j = 0; j < 4; ++j)
                    sc[i][j] += a[i].x * b[j].x + a[i].y * b[j].y
                              + a[i].z * b[j].z + a[i].w * b[j].w;
        }
        if (j0 == q0) {  // diagonal tile: causal mask
            #pragma unroll
            for (int i = 0; i < 4; ++i)
                #pragma unroll
                for (int j = 0; j < 4; ++j)
                    if (tc + 16 * j > tr * 4 + i) sc[i][j] = -3.0e38f;
        }

        // online softmax (rows owned by one wave's 16-lane group -> shuffle reduce)
        float p[4][4];
        #pragma unroll
        for (int i = 0; i < 4; ++i) {
            float rm = sc[i][0];
            #pragma unroll
            for (int j = 1; j < 4; ++j) rm = fmaxf(rm, sc[i][j]);
            #pragma unroll
            for (int off = 1; off < 16; off <<= 1) rm = fmaxf(rm, __shfl_xor(rm, off));
            float nm = fmaxf(m_i[i], rm);
            float alpha = __expf(m_i[i] - nm);
            float rs = 0.f;
            #pragma unroll
            for (int j = 0; j < 4; ++j) { p[i][j] = __expf(sc[i][j] - nm); rs += p[i][j]; }
            #pragma unroll
            for (int off = 1; off < 16; off <<= 1) rs += __shfl_xor(rs, off);
            l_i[i] = l_i[i] * alpha + rs;
            m_i[i] = nm;
            #pragma unroll
            for (int j = 0; j < 4; ++j) acc[i][j] *= alpha;
        }

        __syncthreads();   // all done reading ks as K
        #pragma unroll
        for (int i = 0; i < 4; ++i)
            #pragma unroll
            for (int j = 0; j < 4; ++j)
                ks[tr * 4 + i][tc + 16 * j] = p[i][j];   // P tile
        __syncthreads();

        // acc += P . V
        #pragma unroll
        for (int c0 = 0; c0 < 64; c0 += 4) {
            float pf[4][4];
            #pragma unroll
            for (int i = 0; i < 4; ++i) {
                float4 t4 = *(float4*)&ks[tr * 4 + i][c0];
                pf[i][0] = t4.x; pf[i][1] = t4.y; pf[i][2] = t4.z; pf[i][3] = t4.w;
            }
            #pragma unroll
            for (int cc = 0; cc < 4; ++cc) {
                float vv[4];
                #pragma unroll
                for (int j = 0; j < 4; ++j) vv[j] = vs[c0 + cc][tc + 16 * j];
                #pragma unroll
                for (int i = 0; i < 4; ++i)
                    #pragma unroll
                    for (int j = 0; j < 4; ++j)
                        acc[i][j] += pf[i][cc] * vv[j];
            }
        }
    }

    // normalize and write to Y in (b, s, d_model) layout
    const int b = bh >> 4, h = bh & 15;
    #pragma unroll
    for (int i = 0; i < 4; ++i) {
        float inv = 1.f / l_i[i];
        int gq = q0 + tr * 4 + i;
        #pragma unroll
        for (int j = 0; j < 4; ++j) {
            int c = tc + 16 * j;
            Y[((size_t)(b * SS + gq)) * DM + h * HD + c] = acc[i][j] * inv;
        }
    }
}

extern "C" void kernel_launch(void* const* d_in, const int* in_sizes, int n_in,
                              void* d_out, int out_size, void* d_ws, size_t ws_size,
                              hipStream_t stream)
{
    const float* x       = (const float*)d_in[0];
    const int*   tp      = (const int*)d_in[1];
    const int*   use_rope= (const int*)d_in[2];
    const float* Wq      = (const float*)d_in[3];
    const float* Wk      = (const float*)d_in[4];
    const float* Wv      = (const float*)d_in[5];
    const float* Wo      = (const float*)d_in[6];
    const float* cosp    = (const float*)d_in[7];
    const float* sinp    = (const float*)d_in[8];
    float* out = (float*)d_out;

    const size_t n = (size_t)BB * NH * SS * HD;   // 4M floats per tensor
    float* Qb = (float*)d_ws;
    float* Kb = Qb + n;
    float* Vb = Kb + n;
    float* Yb = Vb + n;

    qkv_gemm<<<dim3(DM / 64, BB * SS / 64, 3), 256, 0, stream>>>(x, Wq, Wk, Wv, Qb, Kb, Vb);
    rope_kernel<<<(BB * NH * SS * 32) / 256, 256, 0, stream>>>(Qb, Kb, tp, cosp, sinp, use_rope);
    attn_kernel<<<dim3(SS / 64, BB * NH), 256, 0, stream>>>(Qb, Kb, Vb, Yb);
    out_gemm<<<dim3(DM / 64, BB * SS / 64), 256, 0, stream>>>(Yb, Wo, out);
}

// Round 2
// 245.177 us; speedup vs baseline: 7.7518x; 7.7518x over previous
//
#include <hip/hip_runtime.h>
#include <math.h>

#define BB 2
#define SS 2048
#define DM 1024
#define NH 16
#define HD 64

typedef __attribute__((ext_vector_type(8))) __bf16 bf16x8;
typedef __attribute__((ext_vector_type(8))) unsigned short u16x8;
typedef __attribute__((ext_vector_type(4))) float f32x4;
typedef unsigned short ushort_t;
typedef unsigned int uint_t;

static __device__ __forceinline__ unsigned short f2bf(float f) {
    unsigned int x = __float_as_uint(f);
    x += 0x7FFF + ((x >> 16) & 1);          // RNE
    return (unsigned short)(x >> 16);
}
static __device__ __forceinline__ float bf2f(unsigned int u) {
    return __uint_as_float(u << 16);
}

// ---------------- fp32 -> bf16 cast ----------------
__global__ __launch_bounds__(256)
void cast_bf16(const float* __restrict__ src, ushort_t* __restrict__ dst, int n4) {
    int i = blockIdx.x * 256 + threadIdx.x;
    if (i >= n4) return;
    float4 v = ((const float4*)src)[i];
    ushort4 o;
    o.x = f2bf(v.x); o.y = f2bf(v.y); o.z = f2bf(v.z); o.w = f2bf(v.w);
    ((ushort4*)dst)[i] = o;
}

// ---------------- QKV projection, bf16 MFMA, 128x128 tile ----------------
// C[i,j] = sum_k X[i,k] * W[j,k]; epilogue scatters to (b,h,s,hd) bf16.
__global__ __launch_bounds__(256)
void qkv_gemm(const ushort_t* __restrict__ X,
              const ushort_t* __restrict__ Wq, const ushort_t* __restrict__ Wk,
              const ushort_t* __restrict__ Wv,
              ushort_t* __restrict__ Q, ushort_t* __restrict__ K, ushort_t* __restrict__ V)
{
    const ushort_t* W; ushort_t* dst;
    if (blockIdx.z == 0)      { W = Wq; dst = Q; }
    else if (blockIdx.z == 1) { W = Wk; dst = K; }
    else                      { W = Wv; dst = V; }

    __shared__ ushort_t As[128][40];   // 32 + 8 pad, rows 16B-aligned
    __shared__ ushort_t Bs[128][40];
    const int t  = threadIdx.x;
    const int i0 = blockIdx.y * 128, j0 = blockIdx.x * 128;
    const int wv = t >> 6, L = t & 63, ln = L & 15, qd = L >> 4;
    const int wm = (wv >> 1) * 64, wn = (wv & 1) * 64;

    f32x4 acc[4][4];
    #pragma unroll
    for (int a = 0; a < 4; ++a)
        #pragma unroll
        for (int b = 0; b < 4; ++b)
            #pragma unroll
            for (int e = 0; e < 4; ++e) acc[a][b][e] = 0.f;

    for (int k0 = 0; k0 < DM; k0 += 32) {
        #pragma unroll
        for (int cc = 0; cc < 2; ++cc) {
            int c = t + cc * 256;
            int row = c >> 2, seg = (c & 3) * 8;
            *(u16x8*)&As[row][seg] = *(const u16x8*)&X[(size_t)(i0 + row) * DM + k0 + seg];
            *(u16x8*)&Bs[row][seg] = *(const u16x8*)&W[(size_t)(j0 + row) * DM + k0 + seg];
        }
        __syncthreads();
        bf16x8 af[4], bf[4];
        #pragma unroll
        for (int mi = 0; mi < 4; ++mi) af[mi] = *(const bf16x8*)&As[wm + mi * 16 + ln][qd * 8];
        #pragma unroll
        for (int ni = 0; ni < 4; ++ni) bf[ni] = *(const bf16x8*)&Bs[wn + ni * 16 + ln][qd * 8];
        #pragma unroll
        for (int mi = 0; mi < 4; ++mi)
            #pragma unroll
            for (int ni = 0; ni < 4; ++ni)
                acc[mi][ni] = __builtin_amdgcn_mfma_f32_16x16x32_bf16(af[mi], bf[ni], acc[mi][ni], 0, 0, 0);
        __syncthreads();
    }

    #pragma unroll
    for (int mi = 0; mi < 4; ++mi)
        #pragma unroll
        for (int ni = 0; ni < 4; ++ni)
            #pragma unroll
            for (int r = 0; r < 4; ++r) {
                int gi = i0 + wm + mi * 16 + qd * 4 + r;
                int gj = j0 + wn + ni * 16 + ln;
                int b = gi >> 11, s = gi & 2047, h = gj >> 6, d = gj & 63;
                dst[(((size_t)(b * NH + h)) * SS + s) * HD + d] = f2bf(acc[mi][ni][r]);
            }
}

// ---------------- output projection, bf16 MFMA -> fp32 out ----------------
__global__ __launch_bounds__(256)
void out_gemm(const ushort_t* __restrict__ X, const ushort_t* __restrict__ W,
              float* __restrict__ dst)
{
    __shared__ ushort_t As[128][40];
    __shared__ ushort_t Bs[128][40];
    const int t  = threadIdx.x;
    const int i0 = blockIdx.y * 128, j0 = blockIdx.x * 128;
    const int wv = t >> 6, L = t & 63, ln = L & 15, qd = L >> 4;
    const int wm = (wv >> 1) * 64, wn = (wv & 1) * 64;

    f32x4 acc[4][4];
    #pragma unroll
    for (int a = 0; a < 4; ++a)
        #pragma unroll
        for (int b = 0; b < 4; ++b)
            #pragma unroll
            for (int e = 0; e < 4; ++e) acc[a][b][e] = 0.f;

    for (int k0 = 0; k0 < DM; k0 += 32) {
        #pragma unroll
        for (int cc = 0; cc < 2; ++cc) {
            int c = t + cc * 256;
            int row = c >> 2, seg = (c & 3) * 8;
            *(u16x8*)&As[row][seg] = *(const u16x8*)&X[(size_t)(i0 + row) * DM + k0 + seg];
            *(u16x8*)&Bs[row][seg] = *(const u16x8*)&W[(size_t)(j0 + row) * DM + k0 + seg];
        }
        __syncthreads();
        bf16x8 af[4], bf[4];
        #pragma unroll
        for (int mi = 0; mi < 4; ++mi) af[mi] = *(const bf16x8*)&As[wm + mi * 16 + ln][qd * 8];
        #pragma unroll
        for (int ni = 0; ni < 4; ++ni) bf[ni] = *(const bf16x8*)&Bs[wn + ni * 16 + ln][qd * 8];
        #pragma unroll
        for (int mi = 0; mi < 4; ++mi)
            #pragma unroll
            for (int ni = 0; ni < 4; ++ni)
                acc[mi][ni] = __builtin_amdgcn_mfma_f32_16x16x32_bf16(af[mi], bf[ni], acc[mi][ni], 0, 0, 0);
        __syncthreads();
    }

    #pragma unroll
    for (int mi = 0; mi < 4; ++mi)
        #pragma unroll
        for (int ni = 0; ni < 4; ++ni)
            #pragma unroll
            for (int r = 0; r < 4; ++r) {
                int gi = i0 + wm + mi * 16 + qd * 4 + r;
                int gj = j0 + wn + ni * 16 + ln;
                dst[(size_t)gi * DM + gj] = acc[mi][ni][r];
            }
}

// ---------------- RoPE on bf16 Q/K ----------------
__global__ __launch_bounds__(256)
void rope_kernel(ushort_t* __restrict__ Q, ushort_t* __restrict__ Kt,
                 const int* __restrict__ tp, const float* __restrict__ cosp,
                 const float* __restrict__ sinp, const int* __restrict__ use_rope)
{
    if (use_rope[0] == 0) return;
    int idx = blockIdx.x * 256 + threadIdx.x;   // B*H*S*32 pairs
    int p = idx & 31, s = (idx >> 5) & 2047, bh = idx >> 16;
    int pos = tp[s];
    float c  = cosp[pos * 32 + p];
    float sn = sinp[pos * 32 + p];
    size_t base = ((size_t)bh * SS + s) * HD + 2 * p;
    uint_t qw = *(uint_t*)&Q[base];
    uint_t kw = *(uint_t*)&Kt[base];
    float qe = bf2f(qw & 0xffffu), qo = bf2f(qw >> 16);
    float ke = bf2f(kw & 0xffffu), ko = bf2f(kw >> 16);
    uint_t qn = (uint_t)f2bf(qe * c - qo * sn) | ((uint_t)f2bf(qo * c + qe * sn) << 16);
    uint_t kn = (uint_t)f2bf(ke * c - ko * sn) | ((uint_t)f2bf(ko * c + ke * sn) << 16);
    *(uint_t*)&Q[base]  = qn;
    *(uint_t*)&Kt[base] = kn;
}

// ---------------- MFMA flash attention ----------------
// Block: 256 thr = 4 waves. 64 q-rows per block (16 per wave). K/V tiles 64.
// Q,K,V bf16 (b,h,s,hd). Y written bf16 (b,s,d_model) for the out-proj GEMM.
__global__ __launch_bounds__(256)
void attn_kernel(const ushort_t* __restrict__ Q, const ushort_t* __restrict__ K,
                 const ushort_t* __restrict__ V, ushort_t* __restrict__ Y)
{
    __shared__ ushort_t Ks[64][72];      // K-tile, row-major over d
    __shared__ ushort_t Vt[64][72];      // V-tile transposed: [d][key]
    __shared__ ushort_t Ps[4][16][72];   // per-wave P round-trip (C-layout -> A-layout)

    const int t  = threadIdx.x;
    const int wv = t >> 6, L = t & 63, ln = L & 15, qd = L >> 4;
    const int bh = blockIdx.x;
    const int qt = gridDim.y - 1 - blockIdx.y;   // longest-first dispatch
    const int q0 = qt * 64;
    const ushort_t* Qp = Q + (size_t)bh * SS * HD;
    const ushort_t* Kp = K + (size_t)bh * SS * HD;
    const ushort_t* Vp = V + (size_t)bh * SS * HD;

    // Q fragments for this wave's 16 rows (A-operand layout), loaded once
    bf16x8 qf[2];
    {
        size_t row = (size_t)(q0 + wv * 16 + ln) * HD;
        qf[0] = *(const bf16x8*)&Qp[row + qd * 8];
        qf[1] = *(const bf16x8*)&Qp[row + 32 + qd * 8];
    }

    f32x4 oacc[4];
    #pragma unroll
    for (int ni = 0; ni < 4; ++ni)
        #pragma unroll
        for (int e = 0; e < 4; ++e) oacc[ni][e] = 0.f;
    float m_i[4], l_i[4];
    #pragma unroll
    for (int r = 0; r < 4; ++r) { m_i[r] = -3.0e38f; l_i[r] = 0.f; }

    const int ntile = qt + 1;
    for (int tix = 0; tix < ntile; ++tix) {
        const int j0 = tix * 64;
        // ---- stage K tile (row-major) ----
        #pragma unroll
        for (int cc = 0; cc < 2; ++cc) {
            int c = t + cc * 256;
            int kr = c >> 3, ksg = (c & 7) * 8;
            *(u16x8*)&Ks[kr][ksg] = *(const u16x8*)&Kp[(size_t)(j0 + kr) * HD + ksg];
        }
        // ---- stage V tile transposed: thread handles 2 adjacent keys x 8 d ----
        {
            int kp = t & 31, ds8 = (t >> 5) * 8;
            u16x8 va = *(const u16x8*)&Vp[(size_t)(j0 + 2 * kp) * HD + ds8];
            u16x8 vb = *(const u16x8*)&Vp[(size_t)(j0 + 2 * kp + 1) * HD + ds8];
            #pragma unroll
            for (int u = 0; u < 8; ++u) {
                uint_t w = (uint_t)va[u] | ((uint_t)vb[u] << 16);
                *(uint_t*)&Vt[ds8 + u][2 * kp] = w;
            }
        }
        __syncthreads();

        // ---- S = Q.K^T (16x64 per wave) ----
        f32x4 sacc[4];
        #pragma unroll
        for (int ct = 0; ct < 4; ++ct) {
            #pragma unroll
            for (int e = 0; e < 4; ++e) sacc[ct][e] = 0.f;
            #pragma unroll
            for (int kc = 0; kc < 2; ++kc) {
                bf16x8 kf = *(const bf16x8*)&Ks[ct * 16 + ln][kc * 32 + qd * 8];
                sacc[ct] = __builtin_amdgcn_mfma_f32_16x16x32_bf16(qf[kc], kf, sacc[ct], 0, 0, 0);
            }
            #pragma unroll
            for (int e = 0; e < 4; ++e) sacc[ct][e] *= 0.125f;   // 1/sqrt(64)
        }
        if (j0 == q0) {   // diagonal tile: causal mask (col > row)
            #pragma unroll
            for (int ct = 0; ct < 4; ++ct)
                #pragma unroll
                for (int r = 0; r < 4; ++r)
                    if (ct * 16 + ln > wv * 16 + qd * 4 + r) sacc[ct][r] = -3.0e38f;
        }

        // ---- online softmax (rows live in 16-lane quad groups) ----
        #pragma unroll
        for (int r = 0; r < 4; ++r) {
            float rm = fmaxf(fmaxf(sacc[0][r], sacc[1][r]), fmaxf(sacc[2][r], sacc[3][r]));
            rm = fmaxf(rm, __shfl_xor(rm, 1));
            rm = fmaxf(rm, __shfl_xor(rm, 2));
            rm = fmaxf(rm, __shfl_xor(rm, 4));
            rm = fmaxf(rm, __shfl_xor(rm, 8));
            float nm = fmaxf(m_i[r], rm);
            float alpha = __expf(m_i[r] - nm);
            float rs = 0.f;
            #pragma unroll
            for (int ct = 0; ct < 4; ++ct) {
                float p = __expf(sacc[ct][r] - nm);
                sacc[ct][r] = p;
                rs += p;
            }
            rs += __shfl_xor(rs, 1);
            rs += __shfl_xor(rs, 2);
            rs += __shfl_xor(rs, 4);
            rs += __shfl_xor(rs, 8);
            l_i[r] = l_i[r] * alpha + rs;
            m_i[r] = nm;
            #pragma unroll
            for (int ni = 0; ni < 4; ++ni) oacc[ni][r] *= alpha;
        }

        // ---- P: C-layout regs -> LDS -> A-operand frags (wave-local) ----
        #pragma unroll
        for (int ct = 0; ct < 4; ++ct)
            #pragma unroll
            for (int r = 0; r < 4; ++r)
                Ps[wv][qd * 4 + r][ct * 16 + ln] = f2bf(sacc[ct][r]);
        bf16x8 pf0 = *(const bf16x8*)&Ps[wv][ln][qd * 8];
        bf16x8 pf1 = *(const bf16x8*)&Ps[wv][ln][32 + qd * 8];

        // ---- O += P.V ----
        #pragma unroll
        for (int ni = 0; ni < 4; ++ni) {
            bf16x8 vf0 = *(const bf16x8*)&Vt[ni * 16 + ln][qd * 8];
            bf16x8 vf1 = *(const bf16x8*)&Vt[ni * 16 + ln][32 + qd * 8];
            oacc[ni] = __builtin_amdgcn_mfma_f32_16x16x32_bf16(pf0, vf0, oacc[ni], 0, 0, 0);
            oacc[ni] = __builtin_amdgcn_mfma_f32_16x16x32_bf16(pf1, vf1, oacc[ni], 0, 0, 0);
        }
        __syncthreads();   // done reading Ks/Vt before next stage
    }

    // ---- epilogue: normalize, write Y bf16 in (b, s, d_model) ----
    const int b = bh >> 4, h = bh & 15;
    #pragma unroll
    for (int r = 0; r < 4; ++r) {
        float inv = 1.f / l_i[r];
        int s = q0 + wv * 16 + qd * 4 + r;
        #pragma unroll
        for (int ni = 0; ni < 4; ++ni) {
            int d = ni * 16 + ln;
            Y[((size_t)(b * SS + s)) * DM + h * HD + d] = f2bf(oacc[ni][r] * inv);
        }
    }
}

extern "C" void kernel_launch(void* const* d_in, const int* in_sizes, int n_in,
                              void* d_out, int out_size, void* d_ws, size_t ws_size,
                              hipStream_t stream)
{
    const float* x        = (const float*)d_in[0];
    const int*   tp       = (const int*)d_in[1];
    const int*   use_rope = (const int*)d_in[2];
    const float* Wq       = (const float*)d_in[3];
    const float* Wk       = (const float*)d_in[4];
    const float* Wv       = (const float*)d_in[5];
    const float* Wo       = (const float*)d_in[6];
    const float* cosp     = (const float*)d_in[7];
    const float* sinp     = (const float*)d_in[8];
    float* out = (float*)d_out;

    char* ws = (char*)d_ws;
    const size_t MB = 1 << 20;
    ushort_t* xb  = (ushort_t*)(ws);
    ushort_t* Wqb = (ushort_t*)(ws + 8 * MB);
    ushort_t* Wkb = (ushort_t*)(ws + 10 * MB);
    ushort_t* Wvb = (ushort_t*)(ws + 12 * MB);
    ushort_t* Wob = (ushort_t*)(ws + 14 * MB);
    ushort_t* Qb  = (ushort_t*)(ws + 16 * MB);
    ushort_t* Kb  = (ushort_t*)(ws + 24 * MB);
    ushort_t* Vb  = (ushort_t*)(ws + 32 * MB);
    ushort_t* Yb  = (ushort_t*)(ws + 40 * MB);

    cast_bf16<<<4096, 256, 0, stream>>>(x,  xb,  (BB * SS * DM) / 4);
    cast_bf16<<<1024, 256, 0, stream>>>(Wq, Wqb, (DM * DM) / 4);
    cast_bf16<<<1024, 256, 0, stream>>>(Wk, Wkb, (DM * DM) / 4);
    cast_bf16<<<1024, 256, 0, stream>>>(Wv, Wvb, (DM * DM) / 4);
    cast_bf16<<<1024, 256, 0, stream>>>(Wo, Wob, (DM * DM) / 4);

    qkv_gemm<<<dim3(DM / 128, BB * SS / 128, 3), 256, 0, stream>>>(xb, Wqb, Wkb, Wvb, Qb, Kb, Vb);
    rope_kernel<<<(BB * NH * SS * 32) / 256, 256, 0, stream>>>(Qb, Kb, tp, cosp, sinp, use_rope);
    attn_kernel<<<dim3(BB * NH, SS / 64), 256, 0, stream>>>(Qb, Kb, Vb, Yb);
    out_gemm<<<dim3(DM / 128, BB * SS / 128), 256, 0, stream>>>(Yb, Wob, out);
}

// Round 3
// 211.013 us; speedup vs baseline: 9.0069x; 1.1619x over previous
//
#include <hip/hip_runtime.h>
#include <math.h>

#define BB 2
#define SS 2048
#define DM 1024
#define NH 16
#define HD 64

typedef __attribute__((ext_vector_type(8))) __bf16 bf16x8;
typedef __attribute__((ext_vector_type(4))) __bf16 bf16x4;
typedef __attribute__((ext_vector_type(8))) unsigned short u16x8;
typedef __attribute__((ext_vector_type(4))) float f32x4;
typedef unsigned short u16;
typedef unsigned int u32;
typedef __attribute__((address_space(1))) unsigned int u32g;
typedef __attribute__((address_space(3))) unsigned int u32l;

#define CEXP 0.18033688011112042f   // 0.125 * log2(e)

static __device__ __forceinline__ u16 f2bf(float f) {
    __bf16 h = (__bf16)f;
    return __builtin_bit_cast(unsigned short, h);
}

// async global->LDS, 16B per lane; lds base must be wave-uniform, lane i lands at base + i*16B
static __device__ __forceinline__ void gld16(const u16* g, u16* l) {
    __builtin_amdgcn_global_load_lds((const u32g*)g, (u32l*)l, 16, 0, 0);
}

// ---------------- fused fp32 -> bf16 cast for x + 4 weights ----------------
__global__ __launch_bounds__(256)
void cast_all(const float* __restrict__ x,
              const float* __restrict__ wq, const float* __restrict__ wk,
              const float* __restrict__ wv, const float* __restrict__ wo,
              u16* __restrict__ xb, u16* __restrict__ wqb, u16* __restrict__ wkb,
              u16* __restrict__ wvb, u16* __restrict__ wob)
{
    const int N4X = (BB * SS * DM) / 4;   // 1048576
    const int N4W = (DM * DM) / 4;        // 262144
    int i = blockIdx.x * 256 + threadIdx.x;
    const float* src; u16* dst; int off;
    if (i < N4X) { src = x; dst = xb; off = i; }
    else {
        int i2 = i - N4X;
        int w = i2 >> 18;           // /262144
        off = i2 & (N4W - 1);
        switch (w) {
            case 0:  src = wq; dst = wqb; break;
            case 1:  src = wk; dst = wkb; break;
            case 2:  src = wv; dst = wvb; break;
            default: src = wo; dst = wob; break;
        }
    }
    float4 v = ((const float4*)src)[off];
    ushort4 o;
    o.x = f2bf(v.x); o.y = f2bf(v.y); o.z = f2bf(v.z); o.w = f2bf(v.w);
    ((ushort4*)dst)[off] = o;
}

// ---------------- QKV projection, m97-style: global_load_lds + 128x128 tile ----------------
__global__ __launch_bounds__(256)
void qkv_gemm(const u16* __restrict__ X,
              const u16* __restrict__ Wq, const u16* __restrict__ Wk,
              const u16* __restrict__ Wv,
              u16* __restrict__ Q, u16* __restrict__ K, u16* __restrict__ V)
{
    const u16* W; u16* dst;
    if (blockIdx.z == 0)      { W = Wq; dst = Q; }
    else if (blockIdx.z == 1) { W = Wk; dst = K; }
    else                      { W = Wv; dst = V; }

    __shared__ u16 As[128 * 32];
    __shared__ u16 Bs[128 * 32];
    const int t  = threadIdx.x;
    const int wv = t >> 6, L = t & 63, ln = L & 15, qd = L >> 4;
    const int i0 = blockIdx.y * 128, j0 = blockIdx.x * 128;
    const int wm = (wv >> 1) * 64, wn = (wv & 1) * 64;
    const int srow = L >> 2, scol = (L & 3) * 8;

    f32x4 acc[4][4];
    #pragma unroll
    for (int a = 0; a < 4; ++a)
        #pragma unroll
        for (int b = 0; b < 4; ++b)
            #pragma unroll
            for (int e = 0; e < 4; ++e) acc[a][b][e] = 0.f;

    for (int k0 = 0; k0 < DM; k0 += 32) {
        __syncthreads();
        gld16(X + (size_t)(i0 + wv * 32 +      srow) * DM + k0 + scol, &As[(wv * 32     ) * 32]);
        gld16(X + (size_t)(i0 + wv * 32 + 16 + srow) * DM + k0 + scol, &As[(wv * 32 + 16) * 32]);
        gld16(W + (size_t)(j0 + wv * 32 +      srow) * DM + k0 + scol, &Bs[(wv * 32     ) * 32]);
        gld16(W + (size_t)(j0 + wv * 32 + 16 + srow) * DM + k0 + scol, &Bs[(wv * 32 + 16) * 32]);
        __syncthreads();
        bf16x8 a[4], b[4];
        #pragma unroll
        for (int mi = 0; mi < 4; ++mi) a[mi] = *(const bf16x8*)&As[(wm + mi * 16 + ln) * 32 + qd * 8];
        #pragma unroll
        for (int ni = 0; ni < 4; ++ni) b[ni] = *(const bf16x8*)&Bs[(wn + ni * 16 + ln) * 32 + qd * 8];
        #pragma unroll
        for (int mi = 0; mi < 4; ++mi)
            #pragma unroll
            for (int ni = 0; ni < 4; ++ni)
                acc[mi][ni] = __builtin_amdgcn_mfma_f32_16x16x32_bf16(a[mi], b[ni], acc[mi][ni], 0, 0, 0);
    }

    #pragma unroll
    for (int mi = 0; mi < 4; ++mi)
        #pragma unroll
        for (int ni = 0; ni < 4; ++ni)
            #pragma unroll
            for (int r = 0; r < 4; ++r) {
                int gi = i0 + wm + mi * 16 + qd * 4 + r;
                int gj = j0 + wn + ni * 16 + ln;
                int b = gi >> 11, s = gi & 2047, h = gj >> 6, d = gj & 63;
                dst[(((size_t)(b * NH + h)) * SS + s) * HD + d] = f2bf(acc[mi][ni][r]);
            }
}

// ---------------- output projection, m97-style, fp32 out ----------------
__global__ __launch_bounds__(256)
void out_gemm(const u16* __restrict__ X, const u16* __restrict__ W,
              float* __restrict__ dst)
{
    __shared__ u16 As[128 * 32];
    __shared__ u16 Bs[128 * 32];
    const int t  = threadIdx.x;
    const int wv = t >> 6, L = t & 63, ln = L & 15, qd = L >> 4;
    const int i0 = blockIdx.y * 128, j0 = blockIdx.x * 128;
    const int wm = (wv >> 1) * 64, wn = (wv & 1) * 64;
    const int srow = L >> 2, scol = (L & 3) * 8;

    f32x4 acc[4][4];
    #pragma unroll
    for (int a = 0; a < 4; ++a)
        #pragma unroll
        for (int b = 0; b < 4; ++b)
            #pragma unroll
            for (int e = 0; e < 4; ++e) acc[a][b][e] = 0.f;

    for (int k0 = 0; k0 < DM; k0 += 32) {
        __syncthreads();
        gld16(X + (size_t)(i0 + wv * 32 +      srow) * DM + k0 + scol, &As[(wv * 32     ) * 32]);
        gld16(X + (size_t)(i0 + wv * 32 + 16 + srow) * DM + k0 + scol, &As[(wv * 32 + 16) * 32]);
        gld16(W + (size_t)(j0 + wv * 32 +      srow) * DM + k0 + scol, &Bs[(wv * 32     ) * 32]);
        gld16(W + (size_t)(j0 + wv * 32 + 16 + srow) * DM + k0 + scol, &Bs[(wv * 32 + 16) * 32]);
        __syncthreads();
        bf16x8 a[4], b[4];
        #pragma unroll
        for (int mi = 0; mi < 4; ++mi) a[mi] = *(const bf16x8*)&As[(wm + mi * 16 + ln) * 32 + qd * 8];
        #pragma unroll
        for (int ni = 0; ni < 4; ++ni) b[ni] = *(const bf16x8*)&Bs[(wn + ni * 16 + ln) * 32 + qd * 8];
        #pragma unroll
        for (int mi = 0; mi < 4; ++mi)
            #pragma unroll
            for (int ni = 0; ni < 4; ++ni)
                acc[mi][ni] = __builtin_amdgcn_mfma_f32_16x16x32_bf16(a[mi], b[ni], acc[mi][ni], 0, 0, 0);
    }

    #pragma unroll
    for (int mi = 0; mi < 4; ++mi)
        #pragma unroll
        for (int ni = 0; ni < 4; ++ni)
            #pragma unroll
            for (int r = 0; r < 4; ++r) {
                int gi = i0 + wm + mi * 16 + qd * 4 + r;
                int gj = j0 + wn + ni * 16 + ln;
                dst[(size_t)gi * DM + gj] = acc[mi][ni][r];
            }
}

// ---------------- RoPE on bf16 Q/K ----------------
__global__ __launch_bounds__(256)
void rope_kernel(u16* __restrict__ Q, u16* __restrict__ Kt,
                 const int* __restrict__ tp, const float* __restrict__ cosp,
                 const float* __restrict__ sinp, const int* __restrict__ use_rope)
{
    if (use_rope[0] == 0) return;
    int idx = blockIdx.x * 256 + threadIdx.x;   // B*H*S*32 pairs
    int p = idx & 31, s = (idx >> 5) & 2047, bh = idx >> 16;
    int pos = tp[s];
    float c  = cosp[pos * 32 + p];
    float sn = sinp[pos * 32 + p];
    size_t base = ((size_t)bh * SS + s) * HD + 2 * p;
    u32 qw = *(u32*)&Q[base];
    u32 kw = *(u32*)&Kt[base];
    float qe = __uint_as_float(qw << 16), qo = __uint_as_float(qw & 0xffff0000u);
    float ke = __uint_as_float(kw << 16), ko = __uint_as_float(kw & 0xffff0000u);
    u32 qn = (u32)f2bf(qe * c - qo * sn) | ((u32)f2bf(qo * c + qe * sn) << 16);
    u32 kn = (u32)f2bf(ke * c - ko * sn) | ((u32)f2bf(ko * c + ke * sn) << 16);
    *(u32*)&Q[base]  = qn;
    *(u32*)&Kt[base] = kn;
}

// ---------------- MFMA flash attention, S^T formulation + paired q-tiles ----------------
// Block = 256 thr = 4 waves, handles q-tiles p and 31-p (perfect balance: 33 units).
// Per wave: 16 rows of each group. S^T = mfma(A=K, B=Q) puts each q-row in one lane.
static __device__ __forceinline__ void group_step(
    const bf16x8 af[4][2], const bf16x8 qf[2], u16* psw,
    int diag, int rowg, int j0, int ln, int qd,
    float& m, float& l, f32x4* o, bf16x8& pf0, bf16x8& pf1)
{
    f32x4 s[4];
    #pragma unroll
    for (int mt = 0; mt < 4; ++mt) {
        #pragma unroll
        for (int e = 0; e < 4; ++e) s[mt][e] = 0.f;
        s[mt] = __builtin_amdgcn_mfma_f32_16x16x32_bf16(af[mt][0], qf[0], s[mt], 0, 0, 0);
        s[mt] = __builtin_amdgcn_mfma_f32_16x16x32_bf16(af[mt][1], qf[1], s[mt], 0, 0, 0);
    }
    if (diag) {
        #pragma unroll
        for (int mt = 0; mt < 4; ++mt)
            #pragma unroll
            for (int r = 0; r < 4; ++r)
                if (j0 + mt * 16 + qd * 4 + r > rowg) s[mt][r] = -3.0e38f;
    }
    // row max: in-lane 16 + 2 shuffles (row ln lives in lanes ln, ln+16, ln+32, ln+48)
    float rm = s[0][0];
    #pragma unroll
    for (int mt = 0; mt < 4; ++mt)
        #pragma unroll
        for (int r = 0; r < 4; ++r) rm = fmaxf(rm, s[mt][r]);
    rm = fmaxf(rm, __shfl_xor(rm, 16));
    rm = fmaxf(rm, __shfl_xor(rm, 32));
    float nm = fmaxf(m, rm);
    float alpha = exp2f((m - nm) * CEXP);
    float nmc = nm * CEXP;
    float rs = 0.f;
    #pragma unroll
    for (int mt = 0; mt < 4; ++mt) {
        bf16x4 pk;
        #pragma unroll
        for (int r = 0; r < 4; ++r) {
            float pv = exp2f(fmaf(s[mt][r], CEXP, -nmc));
            rs += pv;
            pk[r] = (__bf16)pv;
        }
        *(bf16x4*)(psw + ln * 72 + mt * 16 + qd * 4) = pk;   // 8B store, 4 consecutive keys
    }
    rs += __shfl_xor(rs, 16);
    rs += __shfl_xor(rs, 32);
    l = l * alpha + rs;
    m = nm;
    // rescale O (C-layout rows qd*4+r) with alpha broadcast from lane qd*4+r
    #pragma unroll
    for (int r = 0; r < 4; ++r) {
        float ar = __shfl(alpha, qd * 4 + r);
        #pragma unroll
        for (int ni = 0; ni < 4; ++ni) o[ni][r] *= ar;
    }
    // read back P as A-operand frags (wave-local LDS round-trip)
    pf0 = *(const bf16x8*)(psw + ln * 72 + qd * 8);
    pf1 = *(const bf16x8*)(psw + ln * 72 + 32 + qd * 8);
}

__global__ __launch_bounds__(256, 2)
void attn_kernel(const u16* __restrict__ Q, const u16* __restrict__ K,
                 const u16* __restrict__ V, u16* __restrict__ Y)
{
    __shared__ u16 Ks[64 * 64];          // [key][d], 8-chunk XOR swizzle
    __shared__ u16 Vt[64 * 64];          // [d][key], 8-chunk XOR swizzle
    __shared__ u16 Ps[4][2][16 * 72];    // per-wave, per-group P round-trip

    const int t  = threadIdx.x;
    const int wv = t >> 6, L = t & 63, ln = L & 15, qd = L >> 4;
    const int bh = blockIdx.x, p = blockIdx.y;
    const int qbA = p * 64, qbB = (31 - p) * 64;
    const u16* Qp = Q + (size_t)bh * SS * HD;
    const u16* Kp = K + (size_t)bh * SS * HD;
    const u16* Vp = V + (size_t)bh * SS * HD;

    bf16x8 qfA[2], qfB[2];
    {
        const u16* ra = Qp + (size_t)(qbA + wv * 16 + ln) * HD;
        qfA[0] = *(const bf16x8*)(ra + qd * 8);
        qfA[1] = *(const bf16x8*)(ra + 32 + qd * 8);
        const u16* rb = Qp + (size_t)(qbB + wv * 16 + ln) * HD;
        qfB[0] = *(const bf16x8*)(rb + qd * 8);
        qfB[1] = *(const bf16x8*)(rb + 32 + qd * 8);
    }

    f32x4 oA[4], oB[4];
    #pragma unroll
    for (int ni = 0; ni < 4; ++ni)
        #pragma unroll
        for (int e = 0; e < 4; ++e) { oA[ni][e] = 0.f; oB[ni][e] = 0.f; }
    float mA = -3.0e38f, lA = 0.f, mB = -3.0e38f, lB = 0.f;

    const int ntile = 32 - p;
    for (int tix = 0; tix < ntile; ++tix) {
        const int j0 = tix * 64;
        __syncthreads();
        // ---- stage K, swizzled: row kr, chunk c8 at column (c8^(kr&7))*8 ----
        #pragma unroll
        for (int cc = 0; cc < 2; ++cc) {
            int c = t + cc * 256;
            int kr = c >> 3, c8 = c & 7;
            u16x8 val = *(const u16x8*)(Kp + (size_t)(j0 + kr) * HD + c8 * 8);
            *(u16x8*)&Ks[kr * 64 + ((c8 ^ (kr & 7)) * 8)] = val;
        }
        // ---- stage V transposed, swizzled: [d][key], keys packed pairwise ----
        {
            int kp = t & 31, dg = t >> 5;
            const u16* v0 = Vp + (size_t)(j0 + 2 * kp) * HD + dg * 8;
            u16x8 va = *(const u16x8*)v0;
            u16x8 vb = *(const u16x8*)(v0 + HD);
            #pragma unroll
            for (int u = 0; u < 8; ++u) {
                int d = dg * 8 + u;
                u32 w = (u32)va[u] | ((u32)vb[u] << 16);
                *(u32*)&Vt[d * 64 + ((kp >> 2) ^ (d & 7)) * 8 + 2 * (kp & 3)] = w;
            }
        }
        __syncthreads();

        // ---- K fragments (A-operand), shared by both q-groups ----
        bf16x8 af[4][2];
        #pragma unroll
        for (int mt = 0; mt < 4; ++mt)
            #pragma unroll
            for (int kc = 0; kc < 2; ++kc)
                af[mt][kc] = *(const bf16x8*)&Ks[(mt * 16 + ln) * 64 + (((kc * 4 + qd) ^ (ln & 7)) * 8)];

        const bool hasA = (tix <= p);
        bf16x8 pA0, pA1, pB0, pB1;
        if (hasA)
            group_step(af, qfA, &Ps[wv][0][0], tix == p, qbA + wv * 16 + ln, j0, ln, qd,
                       mA, lA, oA, pA0, pA1);
        group_step(af, qfB, &Ps[wv][1][0], tix == ntile - 1, qbB + wv * 16 + ln, j0, ln, qd,
                   mB, lB, oB, pB0, pB1);

        // ---- O += P.V ----
        #pragma unroll
        for (int kc = 0; kc < 2; ++kc)
            #pragma unroll
            for (int ni = 0; ni < 4; ++ni) {
                bf16x8 vf = *(const bf16x8*)&Vt[(ni * 16 + ln) * 64 + (((kc * 4 + qd) ^ (ln & 7)) * 8)];
                if (hasA)
                    oA[ni] = __builtin_amdgcn_mfma_f32_16x16x32_bf16(kc ? pA1 : pA0, vf, oA[ni], 0, 0, 0);
                oB[ni] = __builtin_amdgcn_mfma_f32_16x16x32_bf16(kc ? pB1 : pB0, vf, oB[ni], 0, 0, 0);
            }
    }

    // ---- epilogue: normalize, write Y bf16 (b, s, d_model) ----
    const int b = bh >> 4, h = bh & 15;
    #pragma unroll
    for (int r = 0; r < 4; ++r) {
        float invA = 1.f / __shfl(lA, qd * 4 + r);
        float invB = 1.f / __shfl(lB, qd * 4 + r);
        int sA = qbA + wv * 16 + qd * 4 + r;
        int sB = qbB + wv * 16 + qd * 4 + r;
        #pragma unroll
        for (int ni = 0; ni < 4; ++ni) {
            int d = ni * 16 + ln;
            Y[((size_t)(b * SS + sA)) * DM + h * HD + d] = f2bf(oA[ni][r] * invA);
            Y[((size_t)(b * SS + sB)) * DM + h * HD + d] = f2bf(oB[ni][r] * invB);
        }
    }
}

extern "C" void kernel_launch(void* const* d_in, const int* in_sizes, int n_in,
                              void* d_out, int out_size, void* d_ws, size_t ws_size,
                              hipStream_t stream)
{
    const float* x        = (const float*)d_in[0];
    const int*   tp       = (const int*)d_in[1];
    const int*   use_rope = (const int*)d_in[2];
    const float* Wq       = (const float*)d_in[3];
    const float* Wk       = (const float*)d_in[4];
    const float* Wv       = (const float*)d_in[5];
    const float* Wo       = (const float*)d_in[6];
    const float* cosp     = (const float*)d_in[7];
    const float* sinp     = (const float*)d_in[8];
    float* out = (float*)d_out;

    char* ws = (char*)d_ws;
    const size_t MB = 1 << 20;
    u16* xb  = (u16*)(ws);
    u16* Wqb = (u16*)(ws + 8 * MB);
    u16* Wkb = (u16*)(ws + 10 * MB);
    u16* Wvb = (u16*)(ws + 12 * MB);
    u16* Wob = (u16*)(ws + 14 * MB);
    u16* Qb  = (u16*)(ws + 16 * MB);
    u16* Kb  = (u16*)(ws + 24 * MB);
    u16* Vb  = (u16*)(ws + 32 * MB);
    u16* Yb  = (u16*)(ws + 40 * MB);

    cast_all<<<8192, 256, 0, stream>>>(x, Wq, Wk, Wv, Wo, xb, Wqb, Wkb, Wvb, Wob);
    qkv_gemm<<<dim3(DM / 128, BB * SS / 128, 3), 256, 0, stream>>>(xb, Wqb, Wkb, Wvb, Qb, Kb, Vb);
    rope_kernel<<<(BB * NH * SS * 32) / 256, 256, 0, stream>>>(Qb, Kb, tp, cosp, sinp, use_rope);
    attn_kernel<<<dim3(BB * NH, 16), 256, 0, stream>>>(Qb, Kb, Vb, Yb);
    out_gemm<<<dim3(DM / 128, BB * SS / 128), 256, 0, stream>>>(Yb, Wob, out);
}